// Round 3
// baseline (289.483 us; speedup 1.0000x reference)
//
#include <hip/hip_runtime.h>
#include <math.h>

#define B_  2
#define N_  384
#define C_  256
#define H_  4
#define D_  64
#define NBH (B_*H_)            // 8
#define TSZ (NBH*N_*D_)        // 196608 floats per projected tensor [bh][n][d]
#define ESZ (NBH*N_*N_)        // 1179648 elems per logit matrix
#define SCALE 0.125f           // D^-0.5

typedef _Float16 f16;
typedef f16  f16x8 __attribute__((ext_vector_type(8)));
typedef f16  f16x4 __attribute__((ext_vector_type(4)));
typedef float f32x4 __attribute__((ext_vector_type(4)));

// ---------------------------------------------------------------------------
// Kernel 1: projection (unchanged). proj[t][bh][n][d], t in {a,b,c,v1,v2}, f32.
// ---------------------------------------------------------------------------
__global__ __launch_bounds__(256) void proj_kernel(const float* __restrict__ x,
                                                   const float* __restrict__ W,
                                                   float* __restrict__ proj) {
    __shared__ float Xs[32][68];
    __shared__ float Ws[32][68];
    const int tid = threadIdx.x;
    const int tx = tid & 15, ty = tid >> 4;
    const int m0 = blockIdx.x * 64;
    const int c0 = blockIdx.y * 64;
    const int t  = c0 >> 8;
    const int wbase = ((t >= 3) ? (t + 3) : t) * 256;

    float acc[4][4] = {{0.f}};
    for (int k0 = 0; k0 < 256; k0 += 32) {
        __syncthreads();
#pragma unroll
        for (int l = 0; l < 8; ++l) {
            const int idx = l * 256 + tid;
            const int mi = idx >> 5, kk = idx & 31;
            Xs[kk][mi] = x[(m0 + mi) * 256 + k0 + kk];
            const int rem = (c0 + mi) & 255;
            Ws[kk][mi] = W[(wbase + rem) * 256 + k0 + kk];
        }
        __syncthreads();
#pragma unroll
        for (int kk = 0; kk < 32; ++kk) {
            const float4 xf = *(const float4*)&Xs[kk][ty * 4];
            const float4 wf = *(const float4*)&Ws[kk][tx * 4];
            const float xa[4] = {xf.x, xf.y, xf.z, xf.w};
            const float wa[4] = {wf.x, wf.y, wf.z, wf.w};
#pragma unroll
            for (int q = 0; q < 4; ++q)
#pragma unroll
                for (int p = 0; p < 4; ++p)
                    acc[q][p] += xa[q] * wa[p];
        }
    }
#pragma unroll
    for (int q = 0; q < 4; ++q) {
        const int r = m0 + ty * 4 + q;
        const int b = r / N_;
        const int n = r - b * N_;
#pragma unroll
        for (int p = 0; p < 4; ++p) {
            const int rem = (c0 + tx * 4 + p) & 255;
            const int h = rem >> 6, d = rem & 63;
            proj[t * TSZ + ((b * H_ + h) * N_ + n) * D_ + d] = acc[q][p];
        }
    }
}

// ---------------------------------------------------------------------------
// Kernel 2: exp-logit matrices, all f16 now.
//  q=0: eABt16[bh][j][i]   q=1: eCD16[bh][i][k]   q=2: eEF16[bh][j][k]
// ---------------------------------------------------------------------------
__global__ __launch_bounds__(256) void logits_kernel(const float* __restrict__ proj,
                                                     f16* __restrict__ eabt16,
                                                     f16* __restrict__ ecd16,
                                                     f16* __restrict__ eef16) {
    __shared__ float Xs[32][68];
    __shared__ float Ys[32][68];
    const int tid = threadIdx.x;
    const int tx = tid & 15, ty = tid >> 4;
    const int i0 = blockIdx.x * 64, j0 = blockIdx.y * 64;
    const int q  = blockIdx.z >> 3;
    const int bh = blockIdx.z & 7;
    const int xt = q;
    const int yt = (q == 2) ? 0 : (q + 1);
    const float* Xp = proj + xt * TSZ + bh * N_ * D_;
    const float* Yp = proj + yt * TSZ + bh * N_ * D_;

    float acc[4][4] = {{0.f}};
    for (int k0 = 0; k0 < 64; k0 += 32) {
        __syncthreads();
#pragma unroll
        for (int l = 0; l < 8; ++l) {
            const int idx = l * 256 + tid;
            const int mi = idx >> 5, kk = idx & 31;
            Xs[kk][mi] = Xp[(i0 + mi) * 64 + k0 + kk];
            Ys[kk][mi] = Yp[(j0 + mi) * 64 + k0 + kk];
        }
        __syncthreads();
#pragma unroll
        for (int kk = 0; kk < 32; ++kk) {
            const float4 xf = *(const float4*)&Xs[kk][ty * 4];
            const float4 yf = *(const float4*)&Ys[kk][tx * 4];
            const float xa[4] = {xf.x, xf.y, xf.z, xf.w};
            const float ya[4] = {yf.x, yf.y, yf.z, yf.w};
#pragma unroll
            for (int qq = 0; qq < 4; ++qq)
#pragma unroll
                for (int p = 0; p < 4; ++p)
                    acc[qq][p] += xa[qq] * ya[p];
        }
    }
#pragma unroll
    for (int qq = 0; qq < 4; ++qq)
#pragma unroll
        for (int p = 0; p < 4; ++p) {
            const float e = expf(acc[qq][p] * SCALE);
            const int ii = i0 + ty * 4 + qq;
            const int jj = j0 + tx * 4 + p;
            if (q == 0)      eabt16[(size_t)bh * N_ * N_ + jj * N_ + ii] = (f16)e;
            else if (q == 1) ecd16 [(size_t)bh * N_ * N_ + ii * N_ + jj] = (f16)e;
            else             eef16 [(size_t)bh * N_ * N_ + ii * N_ + jj] = (f16)e;
        }
}

// ---------------------------------------------------------------------------
// Kernel 3 (dominant), j-owning restructure.
// Block = (j-tile 64, d-group of 4, bh); wave w owns d = dg*4+w (64 = den).
// Stage eEF[j-tile][0:384] once in LDS (XOR-swizzled, read-only after) and
// v2 (f16). Loop i-tiles: accumulate R over full K=384 in AGPRs (A-frags
// built on the fly = eCD16 * v2f16), fold ONCE per (i,j,d), atomicAdd the
// j-partial numerators. Only one real barrier per block.
// ---------------------------------------------------------------------------
__global__ __launch_bounds__(256) void triplet_mfma2_kernel(
        const f16*  __restrict__ eabt,   // [bh][j][i]
        const f16*  __restrict__ ecdh,   // [bh][i][k]
        const f16*  __restrict__ eefh,   // [bh][j][k]
        const float* __restrict__ v1,    // [bh][n][64]
        const float* __restrict__ v2,    // [bh][n][64]
        float* __restrict__ numout) {    // [bh][i][68], pre-zeroed, atomic
    __shared__ __align__(16) f16 eefs[64 * 384];   // 49152 B, swizzled 16B blocks
    __shared__ __align__(16) f16 v2s[4 * 384];     //  3072 B

    const int tid  = threadIdx.x;
    const int lane = tid & 63;
    const int w    = tid >> 6;        // wave id = d slot
    const int quad = lane >> 4;
    const int lr   = lane & 15;
    const int j0 = blockIdx.x * 64;
    const int dg = blockIdx.y;        // 0..16
    const int bh = blockIdx.z;
    const int dd = dg * 4 + w;        // 0..67; 64 = denominator, 65..67 waste

    const f16*   eabtb = eabt + (size_t)bh * N_ * N_;
    const f16*   ecdb  = ecdh + (size_t)bh * N_ * N_;
    const f16*   eefb  = eefh + (size_t)bh * N_ * N_;
    const float* v1b   = v1 + (size_t)bh * N_ * D_;
    const float* v2b   = v2 + (size_t)bh * N_ * D_;

    // ---- stage eEF tile [64 rows][48 kb-blocks of 8 f16], kb' = kb ^ (row&7)
    {
        const int row = tid >> 2;
#pragma unroll
        for (int rep = 0; rep < 12; ++rep) {
            const int kb = (tid & 3) + rep * 4;
            *(uint4*)(eefs + row * 384 + ((kb ^ (row & 7)) << 3)) =
                *(const uint4*)(eefb + (j0 + row) * N_ + kb * 8);
        }
    }
    // ---- stage v2 (f16) for the 4 d-slots
#pragma unroll
    for (int rep = 0; rep < 6; ++rep) {
        const int id = rep * 256 + tid;
        const int c = id / 384, k = id - c * 384;
        const int d2 = dg * 4 + c;
        v2s[c * 384 + k] = (f16)((d2 < 64) ? v2b[k * 64 + d2] : 1.0f);
    }
    // ---- v1 for this wave's 4 j rows (registers, reused all kernel)
    float v1r[4];
#pragma unroll
    for (int js = 0; js < 4; ++js)
        v1r[js] = (dd < 64) ? v1b[(j0 + js * 16 + lr) * 64 + dd] : 1.0f;
    __syncthreads();

    const int swzbase = lr & 7;

    for (int it = 0; it < 6; ++it) {
        const int i0 = it * 64;
        __syncthreads();   // no LDS hazard: phase-align waves for L1 reuse of eCD

        f32x4 acc[4][4];   // [isub][js] R-tile accumulators, full-K
#pragma unroll
        for (int a = 0; a < 4; ++a)
#pragma unroll
            for (int b = 0; b < 4; ++b)
                acc[a][b] = (f32x4){0.f, 0.f, 0.f, 0.f};

        f16x8 pf[4];       // eCD prefetch
#pragma unroll
        for (int isub = 0; isub < 4; ++isub)
            pf[isub] = *(const f16x8*)(ecdb + (i0 + isub * 16 + lr) * N_ + quad * 8);

        for (int ks = 0; ks < 12; ++ks) {
            const f16x8 v2f = *(const f16x8*)(v2s + w * 384 + ks * 32 + quad * 8);
            f16x8 af[4];
#pragma unroll
            for (int isub = 0; isub < 4; ++isub)
                af[isub] = pf[isub] * v2f;          // v_pk_mul_f16
            if (ks < 11) {
#pragma unroll
                for (int isub = 0; isub < 4; ++isub)
                    pf[isub] = *(const f16x8*)(ecdb + (i0 + isub * 16 + lr) * N_ +
                                               (ks + 1) * 32 + quad * 8);
            }
#pragma unroll
            for (int js = 0; js < 4; ++js) {
                const f16x8 bf = *(const f16x8*)(eefs + (js * 16 + lr) * 384 +
                                                 (((ks * 4 + quad) ^ swzbase) << 3));
#pragma unroll
                for (int isub = 0; isub < 4; ++isub)
                    acc[isub][js] = __builtin_amdgcn_mfma_f32_16x16x32_f16(
                        af[isub], bf, acc[isub][js], 0, 0, 0);
            }
        }
        // ---- fold once per (i,j,d): numacc[i] = sum_j eABt[j,i]*v1[j]*R[i,j]
        float numacc[16];
#pragma unroll
        for (int r = 0; r < 16; ++r) numacc[r] = 0.f;
#pragma unroll
        for (int js = 0; js < 4; ++js)
#pragma unroll
            for (int isub = 0; isub < 4; ++isub) {
                const f16x4 ab = *(const f16x4*)(eabtb + (j0 + js * 16 + lr) * N_ +
                                                 i0 + isub * 16 + quad * 4);
#pragma unroll
                for (int q = 0; q < 4; ++q)
                    numacc[isub * 4 + q] += (float)ab[q] * (v1r[js] * acc[isub][js][q]);
            }
#pragma unroll
        for (int r = 0; r < 16; ++r) {
            float v = numacc[r];
            v += __shfl_xor(v, 1);
            v += __shfl_xor(v, 2);
            v += __shfl_xor(v, 4);
            v += __shfl_xor(v, 8);
            numacc[r] = v;
        }
        if (lr == 0 && dd <= 64) {
#pragma unroll
            for (int r = 0; r < 16; ++r) {
                const int i = i0 + (r >> 2) * 16 + quad * 4 + (r & 3);
                atomicAdd(&numout[((size_t)bh * N_ + i) * 68 + dd], numacc[r]);
            }
        }
    }
}

// ---------------------------------------------------------------------------
// Kernel 4: out[b,n,h*64+d] = num[bh,n,d] / den[bh,n]  (den at slot 64)
// ---------------------------------------------------------------------------
__global__ __launch_bounds__(256) void finalize_kernel(const float* __restrict__ numw,
                                                       float* __restrict__ out) {
    const int o = blockIdx.x * 256 + threadIdx.x;
    const int b = o / (N_ * C_);
    const int rem = o - b * (N_ * C_);
    const int n = rem >> 8;
    const int cc = rem & 255;
    const int h = cc >> 6, d = cc & 63;
    const float* base = numw + (((size_t)b * H_ + h) * N_ + n) * 68;
    out[o] = base[d] / base[64];
}

extern "C" void kernel_launch(void* const* d_in, const int* in_sizes, int n_in,
                              void* d_out, int out_size, void* d_ws, size_t ws_size,
                              hipStream_t stream) {
    const float* x = (const float*)d_in[0];
    const float* W = (const float*)d_in[1];
    float* ws    = (float*)d_ws;
    float* proj  = ws;                              // 5*TSZ f32
    float* numw  = ws + 5 * TSZ;                    // NBH*N_*68 f32 = 208896
    f16*   eabt  = (f16*)(numw + NBH * N_ * 68);    // ESZ f16
    f16*   eefh  = eabt + ESZ;                      // ESZ f16
    f16*   ecdh  = eefh + ESZ;                      // ESZ f16
    // total ~ 3.9 + 0.84 + 3*2.36 MB ~= 11.9 MB of d_ws

    proj_kernel<<<dim3(12, 20), 256, 0, stream>>>(x, W, proj);
    logits_kernel<<<dim3(6, 6, 24), 256, 0, stream>>>(proj, eabt, ecdh, eefh);
    hipMemsetAsync(numw, 0, (size_t)NBH * N_ * 68 * sizeof(float), stream);
    triplet_mfma2_kernel<<<dim3(6, 17, 8), 256, 0, stream>>>(
        eabt, ecdh, eefh, proj + 3 * TSZ, proj + 4 * TSZ, numw);
    finalize_kernel<<<dim3(768), 256, 0, stream>>>(numw, (float*)d_out);
}